// Round 1
// baseline (138.347 us; speedup 1.0000x reference)
//
#include <hip/hip_runtime.h>
#include <hip/hip_bf16.h>

#define BATCH 8
#define SEQ   512
#define DIM   512
#define NL    64
#define ITILE 16

typedef float f32x4 __attribute__((ext_vector_type(4)));

// Kernel 1: h[b,l,i] = dot(head[b,i,:], W[l,0:512]) + bias[l]
//           d[b,l,j] = dot(dep[b,j,:],  W[l,512:1024])
// One block per (b, 16-row i-tile). LDS-stage the tile (XOR-swizzled),
// each thread owns 1 i-row x 4 l-rows.
__global__ __launch_bounds__(256) void alab_proj(
    const float* __restrict__ head, const float* __restrict__ dep,
    const float* __restrict__ W, const float* __restrict__ bias,
    float* __restrict__ hbuf, float* __restrict__ dbuf)
{
    __shared__ float4 sh[ITILE * (DIM / 4)];   // 32 KB
    __shared__ float4 sd[ITILE * (DIM / 4)];   // 32 KB
    const int t  = threadIdx.x;
    const int b  = blockIdx.x >> 5;            // 32 i-tiles per batch
    const int i0 = (blockIdx.x & 31) * ITILE;

    // Stage 16 contiguous rows (32 KB each of head/dep), coalesced float4.
    const float4* h4 = (const float4*)(head + ((size_t)b * SEQ + i0) * DIM);
    const float4* d4 = (const float4*)(dep  + ((size_t)b * SEQ + i0) * DIM);
    #pragma unroll
    for (int u = t; u < ITILE * (DIM / 4); u += 256) {
        const int row = u >> 7, col = u & 127;
        const int sc  = col ^ (row & 7);       // XOR swizzle: row-stride-2KB would
        sh[row * 128 + sc] = h4[u];            // put all rows' col k in one bank
        sd[row * 128 + sc] = d4[u];
    }
    __syncthreads();

    const int iL = t & 15;                     // i within tile
    const int lg = t >> 4;                     // 0..15; l = lg*4 + r
    const int xm = iL & 7;
    const float4* W4 = (const float4*)W;       // [NL][256] float4, row = 2*DIM

    float acch[4] = {0.f, 0.f, 0.f, 0.f};
    float accd[4] = {0.f, 0.f, 0.f, 0.f};
    for (int k4 = 0; k4 < DIM / 4; ++k4) {
        const float4 hv = sh[iL * 128 + (k4 ^ xm)];
        const float4 dv = sd[iL * 128 + (k4 ^ xm)];
        #pragma unroll
        for (int r = 0; r < 4; ++r) {
            const int l = lg * 4 + r;
            const float4 wh = W4[l * 256 + k4];
            const float4 wd = W4[l * 256 + 128 + k4];
            acch[r] += wh.x * hv.x + wh.y * hv.y + wh.z * hv.z + wh.w * hv.w;
            accd[r] += wd.x * dv.x + wd.y * dv.y + wd.z * dv.z + wd.w * dv.w;
        }
    }

    #pragma unroll
    for (int r = 0; r < 4; ++r) {
        const int l = lg * 4 + r;
        const size_t o = ((size_t)b * NL + l) * SEQ + i0 + iL;
        hbuf[o] = acch[r] + bias[l];           // fold bias into h
        dbuf[o] = accd[r];
    }
}

// Kernel 2: out[((b*NL+l)*SEQ+i)*SEQ+j] = hbuf[(b*NL+l)*SEQ+i] + dbuf[(b*NL+l)*SEQ+j]
// Pure streaming-write kernel; nontemporal float4 stores.
__global__ __launch_bounds__(256) void alab_bcast(
    const float* __restrict__ hbuf, const float* __restrict__ dbuf,
    float* __restrict__ out)
{
    const f32x4* dv4 = (const f32x4*)dbuf;
    f32x4* out4 = (f32x4*)out;
    const size_t total4 = (size_t)BATCH * NL * SEQ * (SEQ / 4);  // 33,554,432
    const size_t stride = (size_t)gridDim.x * blockDim.x;
    for (size_t idx = (size_t)blockIdx.x * blockDim.x + threadIdx.x;
         idx < total4; idx += stride) {
        const int    j4  = (int)(idx & (SEQ / 4 - 1));  // 0..127
        const size_t row = idx >> 7;                    // (b*NL+l)*SEQ + i
        const size_t bl  = row >> 9;                    // b*NL + l
        const float  hv  = hbuf[row];                   // wave-uniform-ish, cached
        const f32x4  dv  = dv4[bl * (SEQ / 4) + j4];    // coalesced, L2-resident
        const f32x4  o   = dv + hv;                     // splat-add
        __builtin_nontemporal_store(o, &out4[idx]);
    }
}

extern "C" void kernel_launch(void* const* d_in, const int* in_sizes, int n_in,
                              void* d_out, int out_size, void* d_ws, size_t ws_size,
                              hipStream_t stream) {
    const float* head = (const float*)d_in[0];
    const float* dep  = (const float*)d_in[1];
    const float* W    = (const float*)d_in[2];
    const float* bias = (const float*)d_in[3];
    float* out  = (float*)d_out;
    float* hbuf = (float*)d_ws;                          // 1 MiB
    float* dbuf = hbuf + (size_t)BATCH * NL * SEQ;       // 1 MiB

    alab_proj<<<BATCH * (SEQ / ITILE), 256, 0, stream>>>(head, dep, W, bias, hbuf, dbuf);
    alab_bcast<<<2048, 256, 0, stream>>>(hbuf, dbuf, out);
}